// Round 3
// baseline (1029.575 us; speedup 1.0000x reference)
//
#include <hip/hip_runtime.h>
#include <cmath>

#define DIM 1024
#define NHEADS 16
#define HDIM 64
#define NB 2
#define SEQ 2048
// M = NB*SEQ = 4096 rows through both GEMMs

// ---------------------------------------------------------------------------
// GEMM (NT): C[M,Nc] = A[M,K] * W[Nc,K]^T (+ bias)
// 128x128 tile, BK=16, 256 threads (4 waves in 2x2), 8x8 accum per thread.
// Double-buffered LDS, one __syncthreads per K-step.
// LDS stored transposed [k][m] with stride 132 (132%32=4 -> banks spread).
// Grid: 1D, XCD-swizzled (nwg % 8 == 0 for all our launches).
// ---------------------------------------------------------------------------
template <bool HAS_BIAS>
__global__ __launch_bounds__(256, 2) void gemm_nt(const float* __restrict__ A,
                                                  const float* __restrict__ W,
                                                  const float* __restrict__ bias,
                                                  float* __restrict__ C,
                                                  int M, int Nc, int K) {
    __shared__ float As[2][16][132];
    __shared__ float Bs[2][16][132];

    // XCD-aware swizzle: contiguous tile chunk per XCD (bijective, nwg%8==0)
    const int nwg  = gridDim.x;
    const int orig = blockIdx.x;
    const int tile = (orig & 7) * (nwg >> 3) + (orig >> 3);
    const int gx   = Nc >> 7;                 // tiles along N
    const int m0   = (tile / gx) * 128;
    const int n0   = (tile % gx) * 128;

    const int t  = threadIdx.x;
    const int w  = t >> 6;            // wave 0..3
    const int l  = t & 63;
    const int wr = (w >> 1) * 64;     // wave row offset in tile
    const int wc = (w & 1) * 64;      // wave col offset
    const int lr = (l >> 3) * 4;      // lane row 0,4,..,28
    const int lc = (l & 7) * 4;       // lane col 0,4,..,28

    // staging: thread covers row t>>1 (0..127), k-chunk (t&1)*8
    const int srow = t >> 1;
    const int skc  = (t & 1) * 8;
    const float* Ap = A + (size_t)(m0 + srow) * K + skc;
    const float* Bp = W + (size_t)(n0 + srow) * K + skc;

    float acc[8][8] = {};

    float4 a0 = *reinterpret_cast<const float4*>(Ap);
    float4 a1 = *reinterpret_cast<const float4*>(Ap + 4);
    float4 b0 = *reinterpret_cast<const float4*>(Bp);
    float4 b1 = *reinterpret_cast<const float4*>(Bp + 4);

    auto stage = [&](int bsel) {
        As[bsel][skc + 0][srow] = a0.x; As[bsel][skc + 1][srow] = a0.y;
        As[bsel][skc + 2][srow] = a0.z; As[bsel][skc + 3][srow] = a0.w;
        As[bsel][skc + 4][srow] = a1.x; As[bsel][skc + 5][srow] = a1.y;
        As[bsel][skc + 6][srow] = a1.z; As[bsel][skc + 7][srow] = a1.w;
        Bs[bsel][skc + 0][srow] = b0.x; Bs[bsel][skc + 1][srow] = b0.y;
        Bs[bsel][skc + 2][srow] = b0.z; Bs[bsel][skc + 3][srow] = b0.w;
        Bs[bsel][skc + 4][srow] = b1.x; Bs[bsel][skc + 5][srow] = b1.y;
        Bs[bsel][skc + 6][srow] = b1.z; Bs[bsel][skc + 7][srow] = b1.w;
    };

    stage(0);
    __syncthreads();

    int buf = 0;
    for (int k0 = 0; k0 < K; k0 += 16) {
        const bool more = (k0 + 16) < K;
        if (more) {  // prefetch next tile into registers (overlaps compute)
            a0 = *reinterpret_cast<const float4*>(Ap + k0 + 16);
            a1 = *reinterpret_cast<const float4*>(Ap + k0 + 20);
            b0 = *reinterpret_cast<const float4*>(Bp + k0 + 16);
            b1 = *reinterpret_cast<const float4*>(Bp + k0 + 20);
        }
#pragma unroll
        for (int k = 0; k < 16; ++k) {
            float a[8], b[8];
            *reinterpret_cast<float4*>(&a[0]) = *reinterpret_cast<const float4*>(&As[buf][k][wr + lr]);
            *reinterpret_cast<float4*>(&a[4]) = *reinterpret_cast<const float4*>(&As[buf][k][wr + 32 + lr]);
            *reinterpret_cast<float4*>(&b[0]) = *reinterpret_cast<const float4*>(&Bs[buf][k][wc + lc]);
            *reinterpret_cast<float4*>(&b[4]) = *reinterpret_cast<const float4*>(&Bs[buf][k][wc + 32 + lc]);
#pragma unroll
            for (int i = 0; i < 8; ++i)
#pragma unroll
                for (int j = 0; j < 8; ++j)
                    acc[i][j] = fmaf(a[i], b[j], acc[i][j]);
        }
        if (more) {
            // writes target buf^1 (nobody reads it this iteration); the single
            // barrier makes them visible and guarantees everyone left buf.
            stage(buf ^ 1);
            __syncthreads();
            buf ^= 1;
        }
    }

#pragma unroll
    for (int ci = 0; ci < 2; ++ci) {
#pragma unroll
        for (int i = 0; i < 4; ++i) {
            const int row = m0 + wr + ci * 32 + lr + i;
#pragma unroll
            for (int cj = 0; cj < 2; ++cj) {
                const int col = n0 + wc + cj * 32 + lc;
                float4 v;
                v.x = acc[ci * 4 + i][cj * 4 + 0];
                v.y = acc[ci * 4 + i][cj * 4 + 1];
                v.z = acc[ci * 4 + i][cj * 4 + 2];
                v.w = acc[ci * 4 + i][cj * 4 + 3];
                if (HAS_BIAS) {
                    const float4 bv = *reinterpret_cast<const float4*>(bias + col);
                    v.x += bv.x; v.y += bv.y; v.z += bv.z; v.w += bv.w;
                }
                *reinterpret_cast<float4*>(&C[(size_t)row * Nc + col]) = v;
            }
        }
    }
}

// ---------------------------------------------------------------------------
// Fused flash-style attention, fp32, GEMM-style register blocking.
// qkv layout: [B, SEQ, 3*DIM], offset s*DIM + h*HDIM + d  (s=0:q,1:k,2:v).
// Block: 256 threads = 16(tx) x 16(ty). Tile: 64 q-rows x 64 keys, 4x4/thread.
//   thread rows  = ty*4+i   (0..63)
//   thread keys  = tx*4+j   (S phase)   / output dims = tx*4+j (PV phase)
// Row-wise softmax reduction across the 16 tx-lanes via __shfl_xor(1,2,4,8)
// (a wave = ty 0..3 x tx 0..15; masks <16 stay inside each 16-lane group).
// P^T stored via register transpose as float4 (b128, no scalar 8-way conflict).
// o written as [B, SEQ, DIM] ready for the proj GEMM.
// ---------------------------------------------------------------------------
__global__ __launch_bounds__(256, 2) void attn_kernel(const float* __restrict__ qkv,
                                                      float* __restrict__ o) {
    __shared__ float Qt[64][68];  // [dim][row], pre-scaled
    __shared__ float Kt[64][68];  // [dim][key]
    __shared__ float Vs[64][68];  // [key][dim]
    __shared__ float Pt[64][68];  // [key][row]

    // XCD swizzle over flattened grid (nwg = 1024, %8==0 -> bijective)
    const int nwg  = gridDim.x;
    const int orig = blockIdx.x;
    const int tile = (orig & 7) * (nwg >> 3) + (orig >> 3);
    const int qt = tile & 31;          // SEQ/64 = 32 q-tiles, fastest
    const int h  = (tile >> 5) & 15;
    const int b  = tile >> 9;

    const int t  = threadIdx.x;
    const int tx = t & 15;
    const int ty = t >> 4;

    const size_t bbase = (size_t)b * SEQ * 3 * DIM;
    const float scale = 0.125f;  // 1/sqrt(64)

    // stage Q tile transposed+scaled: thread covers q-row t>>2, dims (t&3)*16..+15
    {
        const int r  = t >> 2;
        const int d0 = (t & 3) * 16;
        const float* qp = qkv + bbase + (size_t)(qt * 64 + r) * (3 * DIM) + h * HDIM + d0;
#pragma unroll
        for (int i = 0; i < 4; ++i) {
            const float4 v = *reinterpret_cast<const float4*>(qp + i * 4);
            Qt[d0 + i * 4 + 0][r] = v.x * scale;
            Qt[d0 + i * 4 + 1][r] = v.y * scale;
            Qt[d0 + i * 4 + 2][r] = v.z * scale;
            Qt[d0 + i * 4 + 3][r] = v.w * scale;
        }
    }

    float oacc[4][4] = {};
    float mrow[4], lrow[4];
#pragma unroll
    for (int i = 0; i < 4; ++i) { mrow[i] = -INFINITY; lrow[i] = 0.f; }

    for (int kt = 0; kt < SEQ / 64; ++kt) {
        __syncthreads();  // prev iter done reading Kt/Vs/Pt (iter0: Qt staged)

        // stage K (transposed) and V (row-major): thread covers key t>>2, dims (t&3)*16..
        {
            const int key = t >> 2;
            const int d0  = (t & 3) * 16;
            const float* kp = qkv + bbase + (size_t)(kt * 64 + key) * (3 * DIM) + DIM + h * HDIM + d0;
            const float* vp = kp + DIM;
#pragma unroll
            for (int i = 0; i < 4; ++i) {
                const float4 kv = *reinterpret_cast<const float4*>(kp + i * 4);
                Kt[d0 + i * 4 + 0][key] = kv.x;
                Kt[d0 + i * 4 + 1][key] = kv.y;
                Kt[d0 + i * 4 + 2][key] = kv.z;
                Kt[d0 + i * 4 + 3][key] = kv.w;
                *reinterpret_cast<float4*>(&Vs[key][d0 + i * 4]) =
                    *reinterpret_cast<const float4*>(vp + i * 4);
            }
        }
        __syncthreads();

        // S = Q K^T : 4x4 outer-product accumulation over 64 dims
        float s[4][4] = {};
#pragma unroll 16
        for (int d = 0; d < 64; ++d) {
            float4 q4 = *reinterpret_cast<const float4*>(&Qt[d][ty * 4]);
            float4 k4 = *reinterpret_cast<const float4*>(&Kt[d][tx * 4]);
            const float qa[4] = {q4.x, q4.y, q4.z, q4.w};
            const float kb[4] = {k4.x, k4.y, k4.z, k4.w};
#pragma unroll
            for (int i = 0; i < 4; ++i)
#pragma unroll
                for (int j = 0; j < 4; ++j)
                    s[i][j] = fmaf(qa[i], kb[j], s[i][j]);
        }

        // online softmax, rows = ty*4+i, reduce across 16 tx-lanes
#pragma unroll
        for (int i = 0; i < 4; ++i) {
            float pm = fmaxf(fmaxf(s[i][0], s[i][1]), fmaxf(s[i][2], s[i][3]));
            pm = fmaxf(pm, __shfl_xor(pm, 1));
            pm = fmaxf(pm, __shfl_xor(pm, 2));
            pm = fmaxf(pm, __shfl_xor(pm, 4));
            pm = fmaxf(pm, __shfl_xor(pm, 8));
            const float newm = fmaxf(mrow[i], pm);
            float ls = 0.f;
#pragma unroll
            for (int j = 0; j < 4; ++j) {
                s[i][j] = __expf(s[i][j] - newm);
                ls += s[i][j];
            }
            ls += __shfl_xor(ls, 1);
            ls += __shfl_xor(ls, 2);
            ls += __shfl_xor(ls, 4);
            ls += __shfl_xor(ls, 8);
            const float factor = __expf(mrow[i] - newm);
            lrow[i] = lrow[i] * factor + ls;
            mrow[i] = newm;
#pragma unroll
            for (int j = 0; j < 4; ++j) oacc[i][j] *= factor;
        }

        // store P transposed via register transpose: Pt[key][row], b128 stores
#pragma unroll
        for (int j = 0; j < 4; ++j) {
            float4 pv;
            pv.x = s[0][j]; pv.y = s[1][j]; pv.z = s[2][j]; pv.w = s[3][j];
            *reinterpret_cast<float4*>(&Pt[tx * 4 + j][ty * 4]) = pv;
        }

        __syncthreads();  // Pt visible (and S-phase done with Kt)

        // O += P V : 4x4 outer-product over 64 keys
#pragma unroll 16
        for (int c = 0; c < 64; ++c) {
            float4 p4 = *reinterpret_cast<const float4*>(&Pt[c][ty * 4]);
            float4 v4 = *reinterpret_cast<const float4*>(&Vs[c][tx * 4]);
            const float pa[4] = {p4.x, p4.y, p4.z, p4.w};
            const float vb[4] = {v4.x, v4.y, v4.z, v4.w};
#pragma unroll
            for (int i = 0; i < 4; ++i)
#pragma unroll
                for (int j = 0; j < 4; ++j)
                    oacc[i][j] = fmaf(pa[i], vb[j], oacc[i][j]);
        }
    }

    // write O/l : rows ty*4+i, head-dims tx*4..+3
#pragma unroll
    for (int i = 0; i < 4; ++i) {
        const float inv = 1.f / lrow[i];
        float4 v;
        v.x = oacc[i][0] * inv;
        v.y = oacc[i][1] * inv;
        v.z = oacc[i][2] * inv;
        v.w = oacc[i][3] * inv;
        float* op = o + ((size_t)b * SEQ + qt * 64 + ty * 4 + i) * DIM + h * HDIM + tx * 4;
        *reinterpret_cast<float4*>(op) = v;
    }
}

// ---------------------------------------------------------------------------
extern "C" void kernel_launch(void* const* d_in, const int* in_sizes, int n_in,
                              void* d_out, int out_size, void* d_ws, size_t ws_size,
                              hipStream_t stream) {
    const float* x      = (const float*)d_in[0];   // [2,2048,1024]
    const float* w_qkv  = (const float*)d_in[1];   // [3072,1024]
    const float* w_proj = (const float*)d_in[2];   // [1024,1024]
    const float* b_proj = (const float*)d_in[3];   // [1024]
    float* out = (float*)d_out;                    // [2,2048,1024]

    const int M = NB * SEQ;                        // 4096
    float* qkv  = (float*)d_ws;                    // [4096, 3072]  50.3 MB
    float* obuf = qkv + (size_t)M * 3 * DIM;       // [4096, 1024]  16.8 MB

    // 1) QKV projection: grid 32x24 tiles -> 768 blocks (%8==0)
    gemm_nt<false><<<dim3((M / 128) * (3 * DIM / 128)), 256, 0, stream>>>(
        x, w_qkv, nullptr, qkv, M, 3 * DIM, DIM);

    // 2) fused attention: 32 q-tiles x 16 heads x 2 batch = 1024 blocks
    attn_kernel<<<dim3((SEQ / 64) * NHEADS * NB), 256, 0, stream>>>(qkv, obuf);

    // 3) output projection + bias: 32x8 tiles -> 256 blocks (%8==0)
    gemm_nt<true><<<dim3((M / 128) * (DIM / 128)), 256, 0, stream>>>(
        obuf, w_proj, b_proj, out, M, DIM, DIM);
}

// Round 4
// 760.659 us; speedup vs baseline: 1.3535x; 1.3535x over previous
//
#include <hip/hip_runtime.h>
#include <cmath>

#define DIM 1024
#define NHEADS 16
#define HDIM 64
#define NB 2
#define SEQ 2048
// M = NB*SEQ = 4096 rows through both GEMMs

typedef __bf16 bf16x8 __attribute__((ext_vector_type(8)));
typedef float f32x4 __attribute__((ext_vector_type(4)));

// ---------------------------------------------------------------------------
// Split-bf16 MFMA GEMM (NT): C[M,Nc] = A[M,K] * W[Nc,K]^T (+ bias)
// A*B ~= Ahi*Bhi + Alo*Bhi + Ahi*Blo  (fp32 accumulate in MFMA)
// Tile 128x128, BK=32, 256 threads = 4 waves in 2x2 (wave tile 64x64 = 4x4
// fragments of 16x16). mfma_f32_16x16x32_bf16:
//   A-frag: lane holds row (l&15), k = (l>>4)*8 + 0..7  (row-major [r][32] tile)
//   B-frag: lane holds col (l&15), k = (l>>4)*8 + 0..7  (W is [n][k] row-major)
//   C/D   : col = l&15, row = (l>>4)*4 + reg             [verified m89/m91]
// LDS rows padded 32->40 bf16 (80B stride) -> uniform bank spread for both
// the b128 staging writes and the b128 fragment reads.
// Grid: 1D, XCD-swizzled (all launches have nwg % 8 == 0).
// ---------------------------------------------------------------------------
template <bool HAS_BIAS>
__global__ __launch_bounds__(256) void gemm_nt_mfma(const float* __restrict__ A,
                                                    const float* __restrict__ W,
                                                    const float* __restrict__ bias,
                                                    float* __restrict__ C,
                                                    int M, int Nc, int K) {
    __shared__ __align__(16) __bf16 Ah[128][40];
    __shared__ __align__(16) __bf16 Al[128][40];
    __shared__ __align__(16) __bf16 Bh[128][40];
    __shared__ __align__(16) __bf16 Bl[128][40];

    // XCD-aware swizzle (bijective: nwg % 8 == 0)
    const int nwg  = gridDim.x;
    const int orig = blockIdx.x;
    const int tile = (orig & 7) * (nwg >> 3) + (orig >> 3);
    const int gx   = Nc >> 7;
    const int m0   = (tile / gx) * 128;
    const int n0   = (tile % gx) * 128;

    const int t  = threadIdx.x;
    const int w  = t >> 6;
    const int l  = t & 63;
    const int wr = (w >> 1) * 64;   // wave row offset
    const int wc = (w & 1) * 64;    // wave col offset
    const int lr = l & 15;          // fragment row/col lane
    const int kg = l >> 4;          // k-group (8 elements each)

    // staging: thread covers row t>>1 (0..127), k-half (t&1)*16 within BK=32
    const int srow = t >> 1;
    const int skh  = (t & 1) * 16;
    const float* Ap = A + (size_t)(m0 + srow) * K + skh;
    const float* Bp = W + (size_t)(n0 + srow) * K + skh;

    f32x4 acc[4][4] = {};

    for (int k0 = 0; k0 < K; k0 += 32) {
        float4 av[4], bv[4];
#pragma unroll
        for (int i = 0; i < 4; ++i) {
            av[i] = *reinterpret_cast<const float4*>(Ap + k0 + i * 4);
            bv[i] = *reinterpret_cast<const float4*>(Bp + k0 + i * 4);
        }
        __syncthreads();  // previous iteration done reading LDS

        // convert to hi/lo bf16 and stage (2x b128 per matrix per split)
#pragma unroll
        for (int half = 0; half < 2; ++half) {
            bf16x8 vah, val_, vbh, vbl;
#pragma unroll
            for (int q = 0; q < 2; ++q) {
                const float4 va = av[half * 2 + q];
                const float4 vb = bv[half * 2 + q];
                const float fa[4] = {va.x, va.y, va.z, va.w};
                const float fb[4] = {vb.x, vb.y, vb.z, vb.w};
#pragma unroll
                for (int e = 0; e < 4; ++e) {
                    const __bf16 ha = (__bf16)fa[e];
                    vah[q * 4 + e]  = ha;
                    val_[q * 4 + e] = (__bf16)(fa[e] - (float)ha);
                    const __bf16 hb = (__bf16)fb[e];
                    vbh[q * 4 + e]  = hb;
                    vbl[q * 4 + e]  = (__bf16)(fb[e] - (float)hb);
                }
            }
            *reinterpret_cast<bf16x8*>(&Ah[srow][skh + half * 8]) = vah;
            *reinterpret_cast<bf16x8*>(&Al[srow][skh + half * 8]) = val_;
            *reinterpret_cast<bf16x8*>(&Bh[srow][skh + half * 8]) = vbh;
            *reinterpret_cast<bf16x8*>(&Bl[srow][skh + half * 8]) = vbl;
        }
        __syncthreads();  // tiles ready

        // fragment loads (b128) + 48 MFMAs
        bf16x8 fah[4], fal[4], fbh[4], fbl[4];
#pragma unroll
        for (int mi = 0; mi < 4; ++mi) {
            fah[mi] = *reinterpret_cast<const bf16x8*>(&Ah[wr + mi * 16 + lr][kg * 8]);
            fal[mi] = *reinterpret_cast<const bf16x8*>(&Al[wr + mi * 16 + lr][kg * 8]);
        }
#pragma unroll
        for (int nj = 0; nj < 4; ++nj) {
            fbh[nj] = *reinterpret_cast<const bf16x8*>(&Bh[wc + nj * 16 + lr][kg * 8]);
            fbl[nj] = *reinterpret_cast<const bf16x8*>(&Bl[wc + nj * 16 + lr][kg * 8]);
        }
#pragma unroll
        for (int mi = 0; mi < 4; ++mi)
#pragma unroll
            for (int nj = 0; nj < 4; ++nj) {
                acc[mi][nj] = __builtin_amdgcn_mfma_f32_16x16x32_bf16(
                    fah[mi], fbh[nj], acc[mi][nj], 0, 0, 0);
                acc[mi][nj] = __builtin_amdgcn_mfma_f32_16x16x32_bf16(
                    fal[mi], fbh[nj], acc[mi][nj], 0, 0, 0);
                acc[mi][nj] = __builtin_amdgcn_mfma_f32_16x16x32_bf16(
                    fah[mi], fbl[nj], acc[mi][nj], 0, 0, 0);
            }
    }

    // epilogue: row = (l>>4)*4 + reg, col = l&15 within each 16x16 fragment
    const int orow = kg * 4;
#pragma unroll
    for (int mi = 0; mi < 4; ++mi) {
#pragma unroll
        for (int r = 0; r < 4; ++r) {
            const int row = m0 + wr + mi * 16 + orow + r;
#pragma unroll
            for (int nj = 0; nj < 4; ++nj) {
                const int col = n0 + wc + nj * 16 + lr;
                float v = acc[mi][nj][r];
                if (HAS_BIAS) v += bias[col];
                C[(size_t)row * Nc + col] = v;
            }
        }
    }
}

// ---------------------------------------------------------------------------
// Fused flash-style attention, fp32 (UNCHANGED from round 3 — verified).
// ---------------------------------------------------------------------------
__global__ __launch_bounds__(256, 2) void attn_kernel(const float* __restrict__ qkv,
                                                      float* __restrict__ o) {
    __shared__ float Qt[64][68];  // [dim][row], pre-scaled
    __shared__ float Kt[64][68];  // [dim][key]
    __shared__ float Vs[64][68];  // [key][dim]
    __shared__ float Pt[64][68];  // [key][row]

    const int nwg  = gridDim.x;
    const int orig = blockIdx.x;
    const int tile = (orig & 7) * (nwg >> 3) + (orig >> 3);
    const int qt = tile & 31;
    const int h  = (tile >> 5) & 15;
    const int b  = tile >> 9;

    const int t  = threadIdx.x;
    const int tx = t & 15;
    const int ty = t >> 4;

    const size_t bbase = (size_t)b * SEQ * 3 * DIM;
    const float scale = 0.125f;  // 1/sqrt(64)

    {
        const int r  = t >> 2;
        const int d0 = (t & 3) * 16;
        const float* qp = qkv + bbase + (size_t)(qt * 64 + r) * (3 * DIM) + h * HDIM + d0;
#pragma unroll
        for (int i = 0; i < 4; ++i) {
            const float4 v = *reinterpret_cast<const float4*>(qp + i * 4);
            Qt[d0 + i * 4 + 0][r] = v.x * scale;
            Qt[d0 + i * 4 + 1][r] = v.y * scale;
            Qt[d0 + i * 4 + 2][r] = v.z * scale;
            Qt[d0 + i * 4 + 3][r] = v.w * scale;
        }
    }

    float oacc[4][4] = {};
    float mrow[4], lrow[4];
#pragma unroll
    for (int i = 0; i < 4; ++i) { mrow[i] = -INFINITY; lrow[i] = 0.f; }

    for (int kt = 0; kt < SEQ / 64; ++kt) {
        __syncthreads();

        {
            const int key = t >> 2;
            const int d0  = (t & 3) * 16;
            const float* kp = qkv + bbase + (size_t)(kt * 64 + key) * (3 * DIM) + DIM + h * HDIM + d0;
            const float* vp = kp + DIM;
#pragma unroll
            for (int i = 0; i < 4; ++i) {
                const float4 kv = *reinterpret_cast<const float4*>(kp + i * 4);
                Kt[d0 + i * 4 + 0][key] = kv.x;
                Kt[d0 + i * 4 + 1][key] = kv.y;
                Kt[d0 + i * 4 + 2][key] = kv.z;
                Kt[d0 + i * 4 + 3][key] = kv.w;
                *reinterpret_cast<float4*>(&Vs[key][d0 + i * 4]) =
                    *reinterpret_cast<const float4*>(vp + i * 4);
            }
        }
        __syncthreads();

        float s[4][4] = {};
#pragma unroll 16
        for (int d = 0; d < 64; ++d) {
            float4 q4 = *reinterpret_cast<const float4*>(&Qt[d][ty * 4]);
            float4 k4 = *reinterpret_cast<const float4*>(&Kt[d][tx * 4]);
            const float qa[4] = {q4.x, q4.y, q4.z, q4.w};
            const float kb[4] = {k4.x, k4.y, k4.z, k4.w};
#pragma unroll
            for (int i = 0; i < 4; ++i)
#pragma unroll
                for (int j = 0; j < 4; ++j)
                    s[i][j] = fmaf(qa[i], kb[j], s[i][j]);
        }

#pragma unroll
        for (int i = 0; i < 4; ++i) {
            float pm = fmaxf(fmaxf(s[i][0], s[i][1]), fmaxf(s[i][2], s[i][3]));
            pm = fmaxf(pm, __shfl_xor(pm, 1));
            pm = fmaxf(pm, __shfl_xor(pm, 2));
            pm = fmaxf(pm, __shfl_xor(pm, 4));
            pm = fmaxf(pm, __shfl_xor(pm, 8));
            const float newm = fmaxf(mrow[i], pm);
            float ls = 0.f;
#pragma unroll
            for (int j = 0; j < 4; ++j) {
                s[i][j] = __expf(s[i][j] - newm);
                ls += s[i][j];
            }
            ls += __shfl_xor(ls, 1);
            ls += __shfl_xor(ls, 2);
            ls += __shfl_xor(ls, 4);
            ls += __shfl_xor(ls, 8);
            const float factor = __expf(mrow[i] - newm);
            lrow[i] = lrow[i] * factor + ls;
            mrow[i] = newm;
#pragma unroll
            for (int j = 0; j < 4; ++j) oacc[i][j] *= factor;
        }

#pragma unroll
        for (int j = 0; j < 4; ++j) {
            float4 pv;
            pv.x = s[0][j]; pv.y = s[1][j]; pv.z = s[2][j]; pv.w = s[3][j];
            *reinterpret_cast<float4*>(&Pt[tx * 4 + j][ty * 4]) = pv;
        }

        __syncthreads();

#pragma unroll 16
        for (int c = 0; c < 64; ++c) {
            float4 p4 = *reinterpret_cast<const float4*>(&Pt[c][ty * 4]);
            float4 v4 = *reinterpret_cast<const float4*>(&Vs[c][tx * 4]);
            const float pa[4] = {p4.x, p4.y, p4.z, p4.w};
            const float vb[4] = {v4.x, v4.y, v4.z, v4.w};
#pragma unroll
            for (int i = 0; i < 4; ++i)
#pragma unroll
                for (int j = 0; j < 4; ++j)
                    oacc[i][j] = fmaf(pa[i], vb[j], oacc[i][j]);
        }
    }

#pragma unroll
    for (int i = 0; i < 4; ++i) {
        const float inv = 1.f / lrow[i];
        float4 v;
        v.x = oacc[i][0] * inv;
        v.y = oacc[i][1] * inv;
        v.z = oacc[i][2] * inv;
        v.w = oacc[i][3] * inv;
        float* op = o + ((size_t)b * SEQ + qt * 64 + ty * 4 + i) * DIM + h * HDIM + tx * 4;
        *reinterpret_cast<float4*>(op) = v;
    }
}

// ---------------------------------------------------------------------------
extern "C" void kernel_launch(void* const* d_in, const int* in_sizes, int n_in,
                              void* d_out, int out_size, void* d_ws, size_t ws_size,
                              hipStream_t stream) {
    const float* x      = (const float*)d_in[0];   // [2,2048,1024]
    const float* w_qkv  = (const float*)d_in[1];   // [3072,1024]
    const float* w_proj = (const float*)d_in[2];   // [1024,1024]
    const float* b_proj = (const float*)d_in[3];   // [1024]
    float* out = (float*)d_out;                    // [2,2048,1024]

    const int M = NB * SEQ;                        // 4096
    float* qkv  = (float*)d_ws;                    // [4096, 3072]  50.3 MB
    float* obuf = qkv + (size_t)M * 3 * DIM;       // [4096, 1024]  16.8 MB

    // 1) QKV projection: 32x24 tiles -> 768 blocks (%8==0)
    gemm_nt_mfma<false><<<dim3((M / 128) * (3 * DIM / 128)), 256, 0, stream>>>(
        x, w_qkv, nullptr, qkv, M, 3 * DIM, DIM);

    // 2) fused attention: 1024 blocks
    attn_kernel<<<dim3((SEQ / 64) * NHEADS * NB), 256, 0, stream>>>(qkv, obuf);

    // 3) output projection + bias: 32x8 tiles -> 256 blocks (%8==0)
    gemm_nt_mfma<true><<<dim3((M / 128) * (DIM / 128)), 256, 0, stream>>>(
        obuf, w_proj, b_proj, out, M, DIM, DIM);
}

// Round 6
// 499.368 us; speedup vs baseline: 2.0618x; 1.5232x over previous
//
#include <hip/hip_runtime.h>
#include <cmath>

#define DIM 1024
#define NHEADS 16
#define HDIM 64
#define NB 2
#define SEQ 2048
// M = NB*SEQ = 4096 rows through both GEMMs

typedef __bf16 bf16x8 __attribute__((ext_vector_type(8)));
typedef float f32x4 __attribute__((ext_vector_type(4)));

union Bf8 { bf16x8 v; __bf16 e[8]; unsigned short us[8]; };

__device__ __forceinline__ void split_bf(float f, __bf16 &h, __bf16 &l) {
    h = (__bf16)f;
    l = (__bf16)(f - (float)h);
}
__device__ __forceinline__ unsigned int pack_bf(float f) {
    __bf16 h, l;
    split_bf(f, h, l);
    union { __bf16 b; unsigned short u; } ch, cl;
    ch.b = h; cl.b = l;
    return (unsigned int)ch.u | ((unsigned int)cl.u << 16);
}

// ---------------------------------------------------------------------------
// Split-bf16 MFMA GEMM (NT) — UNCHANGED from round 4 (validated).
// ---------------------------------------------------------------------------
template <bool HAS_BIAS>
__global__ __launch_bounds__(256) void gemm_nt_mfma(const float* __restrict__ A,
                                                    const float* __restrict__ W,
                                                    const float* __restrict__ bias,
                                                    float* __restrict__ C,
                                                    int M, int Nc, int K) {
    __shared__ __align__(16) __bf16 Ah[128][40];
    __shared__ __align__(16) __bf16 Al[128][40];
    __shared__ __align__(16) __bf16 Bh[128][40];
    __shared__ __align__(16) __bf16 Bl[128][40];

    const int nwg  = gridDim.x;
    const int orig = blockIdx.x;
    const int tile = (orig & 7) * (nwg >> 3) + (orig >> 3);
    const int gx   = Nc >> 7;
    const int m0   = (tile / gx) * 128;
    const int n0   = (tile % gx) * 128;

    const int t  = threadIdx.x;
    const int w  = t >> 6;
    const int l  = t & 63;
    const int wr = (w >> 1) * 64;
    const int wc = (w & 1) * 64;
    const int lr = l & 15;
    const int kg = l >> 4;

    const int srow = t >> 1;
    const int skh  = (t & 1) * 16;
    const float* Ap = A + (size_t)(m0 + srow) * K + skh;
    const float* Bp = W + (size_t)(n0 + srow) * K + skh;

    f32x4 acc[4][4] = {};

    for (int k0 = 0; k0 < K; k0 += 32) {
        float4 av[4], bv[4];
#pragma unroll
        for (int i = 0; i < 4; ++i) {
            av[i] = *reinterpret_cast<const float4*>(Ap + k0 + i * 4);
            bv[i] = *reinterpret_cast<const float4*>(Bp + k0 + i * 4);
        }
        __syncthreads();

#pragma unroll
        for (int half = 0; half < 2; ++half) {
            Bf8 vah, val_, vbh, vbl;
#pragma unroll
            for (int q = 0; q < 2; ++q) {
                const float4 va = av[half * 2 + q];
                const float4 vb = bv[half * 2 + q];
                const float fa[4] = {va.x, va.y, va.z, va.w};
                const float fb[4] = {vb.x, vb.y, vb.z, vb.w};
#pragma unroll
                for (int e = 0; e < 4; ++e) {
                    split_bf(fa[e], vah.e[q * 4 + e], val_.e[q * 4 + e]);
                    split_bf(fb[e], vbh.e[q * 4 + e], vbl.e[q * 4 + e]);
                }
            }
            *reinterpret_cast<bf16x8*>(&Ah[srow][skh + half * 8]) = vah.v;
            *reinterpret_cast<bf16x8*>(&Al[srow][skh + half * 8]) = val_.v;
            *reinterpret_cast<bf16x8*>(&Bh[srow][skh + half * 8]) = vbh.v;
            *reinterpret_cast<bf16x8*>(&Bl[srow][skh + half * 8]) = vbl.v;
        }
        __syncthreads();

        bf16x8 fah[4], fal[4], fbh[4], fbl[4];
#pragma unroll
        for (int mi = 0; mi < 4; ++mi) {
            fah[mi] = *reinterpret_cast<const bf16x8*>(&Ah[wr + mi * 16 + lr][kg * 8]);
            fal[mi] = *reinterpret_cast<const bf16x8*>(&Al[wr + mi * 16 + lr][kg * 8]);
        }
#pragma unroll
        for (int nj = 0; nj < 4; ++nj) {
            fbh[nj] = *reinterpret_cast<const bf16x8*>(&Bh[wc + nj * 16 + lr][kg * 8]);
            fbl[nj] = *reinterpret_cast<const bf16x8*>(&Bl[wc + nj * 16 + lr][kg * 8]);
        }
#pragma unroll
        for (int mi = 0; mi < 4; ++mi)
#pragma unroll
            for (int nj = 0; nj < 4; ++nj) {
                acc[mi][nj] = __builtin_amdgcn_mfma_f32_16x16x32_bf16(
                    fah[mi], fbh[nj], acc[mi][nj], 0, 0, 0);
                acc[mi][nj] = __builtin_amdgcn_mfma_f32_16x16x32_bf16(
                    fal[mi], fbh[nj], acc[mi][nj], 0, 0, 0);
                acc[mi][nj] = __builtin_amdgcn_mfma_f32_16x16x32_bf16(
                    fah[mi], fbl[nj], acc[mi][nj], 0, 0, 0);
            }
    }

    const int orow = kg * 4;
#pragma unroll
    for (int mi = 0; mi < 4; ++mi) {
#pragma unroll
        for (int r = 0; r < 4; ++r) {
            const int row = m0 + wr + mi * 16 + orow + r;
#pragma unroll
            for (int nj = 0; nj < 4; ++nj) {
                const int col = n0 + wc + nj * 16 + lr;
                float v = acc[mi][nj][r];
                if (HAS_BIAS) v += bias[col];
                C[(size_t)row * Nc + col] = v;
            }
        }
    }
}

// ---------------------------------------------------------------------------
// Fused flash attention, split-bf16 MFMA.
// qkv: [B, SEQ, 3*DIM], offsets 0/DIM/2*DIM for q/k/v, + h*HDIM.
// Block: 256 thr = 4 waves; Q-tile 128 rows (wave owns 32: mi 0..1), KV-tile 64.
// S = Q*K^T: A=Q[row][dim], B=K[key][dim] (both row-major in k=dim) — the
//   exact operand/fragment pattern validated by gemm_nt_mfma.
// PV: A=P[row][key], B=V^T[dim][key] (V transposed at staging).
// C/D frags: col=l&15, row=kg*4+reg  [validated].
// Softmax: rows live at (mi, kg, r); reduce over nj in-reg + shfl_xor 1/2/4/8.
// P stored packed u32 (hi | lo<<16) to halve LDS store count + LDS size.
// LDS total ~106KB (static >64KB proven OK in rounds 3/4).
// ---------------------------------------------------------------------------
__global__ __launch_bounds__(256, 1) void attn_mfma(const float* __restrict__ qkv,
                                                    float* __restrict__ o) {
    __shared__ __align__(16) __bf16 Qhi[128][72];
    __shared__ __align__(16) __bf16 Qlo[128][72];
    __shared__ __align__(16) __bf16 Khi[64][72];
    __shared__ __align__(16) __bf16 Klo[64][72];
    __shared__ __align__(16) __bf16 Vhi[64][72];   // [dim][key]
    __shared__ __align__(16) __bf16 Vlo[64][72];   // [dim][key]
    __shared__ __align__(16) unsigned int P32[128][68];

    // 512 blocks = 16 qtiles x 16 heads x 2 batch; XCD swizzle (512 % 8 == 0)
    const int nwg  = gridDim.x;
    const int orig = blockIdx.x;
    const int tile = (orig & 7) * (nwg >> 3) + (orig >> 3);
    const int qt = tile & 15;
    const int h  = (tile >> 4) & 15;
    const int b  = tile >> 8;

    const int t  = threadIdx.x;
    const int w  = t >> 6;
    const int l  = t & 63;
    const int lr = l & 15;
    const int kg = l >> 4;
    const int wq = w * 32;              // wave's q-row base within tile

    const size_t bbase = (size_t)b * SEQ * 3 * DIM;
    const int    hoff  = h * HDIM;

    // ---- stage Q once: scaled by 1/8, split hi/lo (thread: row t>>1, 32 dims)
    {
        const int row = t >> 1;
        const int d0  = (t & 1) * 32;
        const float* qp = qkv + bbase + (size_t)(qt * 128 + row) * (3 * DIM) + hoff + d0;
#pragma unroll
        for (int c = 0; c < 4; ++c) {
            Bf8 hh, ll;
#pragma unroll
            for (int q = 0; q < 2; ++q) {
                const float4 v = *reinterpret_cast<const float4*>(qp + c * 8 + q * 4);
                const float f[4] = {v.x, v.y, v.z, v.w};
#pragma unroll
                for (int e = 0; e < 4; ++e)
                    split_bf(f[e] * 0.125f, hh.e[q * 4 + e], ll.e[q * 4 + e]);
            }
            *reinterpret_cast<bf16x8*>(&Qhi[row][d0 + c * 8]) = hh.v;
            *reinterpret_cast<bf16x8*>(&Qlo[row][d0 + c * 8]) = ll.v;
        }
    }

    // staging assignments for K (row-major) and V (transposed)
    const int skey = t >> 2;            // 0..63
    const int sd0  = (t & 3) * 16;      // 16 dims
    const int vkey = t & 63;
    const int vd0  = (t >> 6) * 16;     // 16 dims per wave

    const float* kptr = qkv + bbase + DIM + hoff + (size_t)skey * (3 * DIM) + sd0;
    const float* vptr = qkv + bbase + 2 * DIM + hoff + (size_t)vkey * (3 * DIM) + vd0;
    const size_t kvstep = (size_t)64 * 3 * DIM;   // 64 keys per tile

    float4 kreg[4], vreg[4];
#pragma unroll
    for (int i = 0; i < 4; ++i) {
        kreg[i] = *reinterpret_cast<const float4*>(kptr + i * 4);
        vreg[i] = *reinterpret_cast<const float4*>(vptr + i * 4);
    }

    f32x4 oacc[2][4] = {};
    float mrow[2][4], lrow[2][4];
#pragma unroll
    for (int mi = 0; mi < 2; ++mi)
#pragma unroll
        for (int r = 0; r < 4; ++r) { mrow[mi][r] = -INFINITY; lrow[mi][r] = 0.f; }

    for (int kt = 0; kt < SEQ / 64; ++kt) {
        __syncthreads();   // prior tile fully consumed (K/V/P free to overwrite)

        // ---- write K tile (split hi/lo, row-major [key][dim])
#pragma unroll
        for (int c = 0; c < 2; ++c) {
            Bf8 hh, ll;
#pragma unroll
            for (int q = 0; q < 2; ++q) {
                const float4 v = kreg[c * 2 + q];
                const float f[4] = {v.x, v.y, v.z, v.w};
#pragma unroll
                for (int e = 0; e < 4; ++e)
                    split_bf(f[e], hh.e[q * 4 + e], ll.e[q * 4 + e]);
            }
            *reinterpret_cast<bf16x8*>(&Khi[skey][sd0 + c * 8]) = hh.v;
            *reinterpret_cast<bf16x8*>(&Klo[skey][sd0 + c * 8]) = ll.v;
        }
        // ---- write V tile transposed ([dim][key]); lane==key -> conflict-free
#pragma unroll
        for (int i = 0; i < 4; ++i) {
            const float f[4] = {vreg[i].x, vreg[i].y, vreg[i].z, vreg[i].w};
#pragma unroll
            for (int e = 0; e < 4; ++e) {
                __bf16 hh, ll;
                split_bf(f[e], hh, ll);
                Vhi[vd0 + i * 4 + e][vkey] = hh;
                Vlo[vd0 + i * 4 + e][vkey] = ll;
            }
        }
        __syncthreads();   // K/V ready

        // ---- prefetch next K/V tile into registers (hides HBM under compute)
        if (kt < SEQ / 64 - 1) {
            const float* kp = kptr + (size_t)(kt + 1) * kvstep;
            const float* vp = vptr + (size_t)(kt + 1) * kvstep;
#pragma unroll
            for (int i = 0; i < 4; ++i) {
                kreg[i] = *reinterpret_cast<const float4*>(kp + i * 4);
                vreg[i] = *reinterpret_cast<const float4*>(vp + i * 4);
            }
        }

        // ---- S = Q K^T  (3-term split)
        f32x4 sacc[2][4] = {};
#pragma unroll
        for (int ks = 0; ks < 2; ++ks) {
            bf16x8 qh[2], ql[2];
#pragma unroll
            for (int mi = 0; mi < 2; ++mi) {
                qh[mi] = *reinterpret_cast<const bf16x8*>(&Qhi[wq + mi * 16 + lr][ks * 32 + kg * 8]);
                ql[mi] = *reinterpret_cast<const bf16x8*>(&Qlo[wq + mi * 16 + lr][ks * 32 + kg * 8]);
            }
#pragma unroll
            for (int nj = 0; nj < 4; ++nj) {
                const bf16x8 kh = *reinterpret_cast<const bf16x8*>(&Khi[nj * 16 + lr][ks * 32 + kg * 8]);
                const bf16x8 kl = *reinterpret_cast<const bf16x8*>(&Klo[nj * 16 + lr][ks * 32 + kg * 8]);
#pragma unroll
                for (int mi = 0; mi < 2; ++mi) {
                    sacc[mi][nj] = __builtin_amdgcn_mfma_f32_16x16x32_bf16(qh[mi], kh, sacc[mi][nj], 0, 0, 0);
                    sacc[mi][nj] = __builtin_amdgcn_mfma_f32_16x16x32_bf16(ql[mi], kh, sacc[mi][nj], 0, 0, 0);
                    sacc[mi][nj] = __builtin_amdgcn_mfma_f32_16x16x32_bf16(qh[mi], kl, sacc[mi][nj], 0, 0, 0);
                }
            }
        }

        // ---- online softmax (rows at (mi, kg, r); keys = nj*16 + l&15)
#pragma unroll
        for (int mi = 0; mi < 2; ++mi) {
#pragma unroll
            for (int r = 0; r < 4; ++r) {
                const float s0 = sacc[mi][0][r], s1 = sacc[mi][1][r];
                const float s2 = sacc[mi][2][r], s3 = sacc[mi][3][r];
                float pm = fmaxf(fmaxf(s0, s1), fmaxf(s2, s3));
                pm = fmaxf(pm, __shfl_xor(pm, 1));
                pm = fmaxf(pm, __shfl_xor(pm, 2));
                pm = fmaxf(pm, __shfl_xor(pm, 4));
                pm = fmaxf(pm, __shfl_xor(pm, 8));
                const float nm = fmaxf(mrow[mi][r], pm);
                const float p0 = __expf(s0 - nm), p1 = __expf(s1 - nm);
                const float p2 = __expf(s2 - nm), p3 = __expf(s3 - nm);
                float ls = (p0 + p1) + (p2 + p3);
                ls += __shfl_xor(ls, 1);
                ls += __shfl_xor(ls, 2);
                ls += __shfl_xor(ls, 4);
                ls += __shfl_xor(ls, 8);
                const float fac = __expf(mrow[mi][r] - nm);
                mrow[mi][r] = nm;
                lrow[mi][r] = lrow[mi][r] * fac + ls;
#pragma unroll
                for (int njd = 0; njd < 4; ++njd) oacc[mi][njd][r] *= fac;
                const int prow = wq + mi * 16 + kg * 4 + r;
                P32[prow][0 * 16 + lr] = pack_bf(p0);
                P32[prow][1 * 16 + lr] = pack_bf(p1);
                P32[prow][2 * 16 + lr] = pack_bf(p2);
                P32[prow][3 * 16 + lr] = pack_bf(p3);
            }
        }
        __syncthreads();   // P visible

        // ---- O += P V  (A = P[row][key], B = V^T[dim][key])
#pragma unroll
        for (int ks = 0; ks < 2; ++ks) {
            bf16x8 ph[2], pl[2];
#pragma unroll
            for (int mi = 0; mi < 2; ++mi) {
                const unsigned int* pp = &P32[wq + mi * 16 + lr][ks * 32 + kg * 8];
                const uint4 u0 = *reinterpret_cast<const uint4*>(pp);
                const uint4 u1 = *reinterpret_cast<const uint4*>(pp + 4);
                const unsigned int uu[8] = {u0.x, u0.y, u0.z, u0.w, u1.x, u1.y, u1.z, u1.w};
                Bf8 hh, ll;
#pragma unroll
                for (int j = 0; j < 8; ++j) {
                    hh.us[j] = (unsigned short)(uu[j] & 0xffffu);
                    ll.us[j] = (unsigned short)(uu[j] >> 16);
                }
                ph[mi] = hh.v;
                pl[mi] = ll.v;
            }
#pragma unroll
            for (int njd = 0; njd < 4; ++njd) {
                const bf16x8 vh = *reinterpret_cast<const bf16x8*>(&Vhi[njd * 16 + lr][ks * 32 + kg * 8]);
                const bf16x8 vl = *reinterpret_cast<const bf16x8*>(&Vlo[njd * 16 + lr][ks * 32 + kg * 8]);
#pragma unroll
                for (int mi = 0; mi < 2; ++mi) {
                    oacc[mi][njd] = __builtin_amdgcn_mfma_f32_16x16x32_bf16(ph[mi], vh, oacc[mi][njd], 0, 0, 0);
                    oacc[mi][njd] = __builtin_amdgcn_mfma_f32_16x16x32_bf16(pl[mi], vh, oacc[mi][njd], 0, 0, 0);
                    oacc[mi][njd] = __builtin_amdgcn_mfma_f32_16x16x32_bf16(ph[mi], vl, oacc[mi][njd], 0, 0, 0);
                }
            }
        }
    }

    // ---- epilogue: normalize and write O [B*SEQ, DIM] head-major cols
#pragma unroll
    for (int mi = 0; mi < 2; ++mi) {
#pragma unroll
        for (int r = 0; r < 4; ++r) {
            const float inv = 1.f / lrow[mi][r];
            const int grow = b * SEQ + qt * 128 + wq + mi * 16 + kg * 4 + r;
#pragma unroll
            for (int njd = 0; njd < 4; ++njd)
                o[(size_t)grow * DIM + hoff + njd * 16 + lr] = oacc[mi][njd][r] * inv;
        }
    }
}

// ---------------------------------------------------------------------------
extern "C" void kernel_launch(void* const* d_in, const int* in_sizes, int n_in,
                              void* d_out, int out_size, void* d_ws, size_t ws_size,
                              hipStream_t stream) {
    const float* x      = (const float*)d_in[0];   // [2,2048,1024]
    const float* w_qkv  = (const float*)d_in[1];   // [3072,1024]
    const float* w_proj = (const float*)d_in[2];   // [1024,1024]
    const float* b_proj = (const float*)d_in[3];   // [1024]
    float* out = (float*)d_out;                    // [2,2048,1024]

    const int M = NB * SEQ;                        // 4096
    float* qkv  = (float*)d_ws;                    // [4096, 3072]
    float* obuf = qkv + (size_t)M * 3 * DIM;       // [4096, 1024]

    // 1) QKV projection: 768 blocks (%8==0)
    gemm_nt_mfma<false><<<dim3((M / 128) * (3 * DIM / 128)), 256, 0, stream>>>(
        x, w_qkv, nullptr, qkv, M, 3 * DIM, DIM);

    // 2) fused attention: 512 blocks (%8==0)
    attn_mfma<<<dim3((SEQ / 128) * NHEADS * NB), 256, 0, stream>>>(qkv, obuf);

    // 3) output projection + bias: 256 blocks (%8==0)
    gemm_nt_mfma<true><<<dim3((M / 128) * (DIM / 128)), 256, 0, stream>>>(
        obuf, w_proj, b_proj, out, M, DIM, DIM);
}

// Round 8
// 403.984 us; speedup vs baseline: 2.5486x; 1.2361x over previous
//
#include <hip/hip_runtime.h>
#include <cmath>

#define DIM 1024
#define NHEADS 16
#define HDIM 64
#define NB 2
#define SEQ 2048
// M = NB*SEQ = 4096 rows through both GEMMs

typedef __bf16 bf16x8 __attribute__((ext_vector_type(8)));
typedef float f32x4 __attribute__((ext_vector_type(4)));

union Bf8 { bf16x8 v; __bf16 e[8]; unsigned short us[8]; };
union Bf1 { __bf16 b; unsigned short u; };

__device__ __forceinline__ void split_bf(float f, __bf16 &h, __bf16 &l) {
    h = (__bf16)f;
    l = (__bf16)(f - (float)h);
}
__device__ __forceinline__ unsigned int pack_bf(float f) {
    __bf16 h, l;
    split_bf(f, h, l);
    Bf1 ch, cl;
    ch.b = h; cl.b = l;
    return (unsigned int)ch.u | ((unsigned int)cl.u << 16);
}

// ---------------------------------------------------------------------------
// Split-bf16 MFMA GEMM (NT) — UNCHANGED from round 4 (validated).
// ---------------------------------------------------------------------------
template <bool HAS_BIAS>
__global__ __launch_bounds__(256) void gemm_nt_mfma(const float* __restrict__ A,
                                                    const float* __restrict__ W,
                                                    const float* __restrict__ bias,
                                                    float* __restrict__ C,
                                                    int M, int Nc, int K) {
    __shared__ __align__(16) __bf16 Ah[128][40];
    __shared__ __align__(16) __bf16 Al[128][40];
    __shared__ __align__(16) __bf16 Bh[128][40];
    __shared__ __align__(16) __bf16 Bl[128][40];

    const int nwg  = gridDim.x;
    const int orig = blockIdx.x;
    const int tile = (orig & 7) * (nwg >> 3) + (orig >> 3);
    const int gx   = Nc >> 7;
    const int m0   = (tile / gx) * 128;
    const int n0   = (tile % gx) * 128;

    const int t  = threadIdx.x;
    const int w  = t >> 6;
    const int l  = t & 63;
    const int wr = (w >> 1) * 64;
    const int wc = (w & 1) * 64;
    const int lr = l & 15;
    const int kg = l >> 4;

    const int srow = t >> 1;
    const int skh  = (t & 1) * 16;
    const float* Ap = A + (size_t)(m0 + srow) * K + skh;
    const float* Bp = W + (size_t)(n0 + srow) * K + skh;

    f32x4 acc[4][4] = {};

    for (int k0 = 0; k0 < K; k0 += 32) {
        float4 av[4], bv[4];
#pragma unroll
        for (int i = 0; i < 4; ++i) {
            av[i] = *reinterpret_cast<const float4*>(Ap + k0 + i * 4);
            bv[i] = *reinterpret_cast<const float4*>(Bp + k0 + i * 4);
        }
        __syncthreads();

#pragma unroll
        for (int half = 0; half < 2; ++half) {
            Bf8 vah, val_, vbh, vbl;
#pragma unroll
            for (int q = 0; q < 2; ++q) {
                const float4 va = av[half * 2 + q];
                const float4 vb = bv[half * 2 + q];
                const float fa[4] = {va.x, va.y, va.z, va.w};
                const float fb[4] = {vb.x, vb.y, vb.z, vb.w};
#pragma unroll
                for (int e = 0; e < 4; ++e) {
                    split_bf(fa[e], vah.e[q * 4 + e], val_.e[q * 4 + e]);
                    split_bf(fb[e], vbh.e[q * 4 + e], vbl.e[q * 4 + e]);
                }
            }
            *reinterpret_cast<bf16x8*>(&Ah[srow][skh + half * 8]) = vah.v;
            *reinterpret_cast<bf16x8*>(&Al[srow][skh + half * 8]) = val_.v;
            *reinterpret_cast<bf16x8*>(&Bh[srow][skh + half * 8]) = vbh.v;
            *reinterpret_cast<bf16x8*>(&Bl[srow][skh + half * 8]) = vbl.v;
        }
        __syncthreads();

        bf16x8 fah[4], fal[4], fbh[4], fbl[4];
#pragma unroll
        for (int mi = 0; mi < 4; ++mi) {
            fah[mi] = *reinterpret_cast<const bf16x8*>(&Ah[wr + mi * 16 + lr][kg * 8]);
            fal[mi] = *reinterpret_cast<const bf16x8*>(&Al[wr + mi * 16 + lr][kg * 8]);
        }
#pragma unroll
        for (int nj = 0; nj < 4; ++nj) {
            fbh[nj] = *reinterpret_cast<const bf16x8*>(&Bh[wc + nj * 16 + lr][kg * 8]);
            fbl[nj] = *reinterpret_cast<const bf16x8*>(&Bl[wc + nj * 16 + lr][kg * 8]);
        }
#pragma unroll
        for (int mi = 0; mi < 4; ++mi)
#pragma unroll
            for (int nj = 0; nj < 4; ++nj) {
                acc[mi][nj] = __builtin_amdgcn_mfma_f32_16x16x32_bf16(
                    fah[mi], fbh[nj], acc[mi][nj], 0, 0, 0);
                acc[mi][nj] = __builtin_amdgcn_mfma_f32_16x16x32_bf16(
                    fal[mi], fbh[nj], acc[mi][nj], 0, 0, 0);
                acc[mi][nj] = __builtin_amdgcn_mfma_f32_16x16x32_bf16(
                    fah[mi], fbl[nj], acc[mi][nj], 0, 0, 0);
            }
    }

    const int orow = kg * 4;
#pragma unroll
    for (int mi = 0; mi < 4; ++mi) {
#pragma unroll
        for (int r = 0; r < 4; ++r) {
            const int row = m0 + wr + mi * 16 + orow + r;
#pragma unroll
            for (int nj = 0; nj < 4; ++nj) {
                const int col = n0 + wc + nj * 16 + lr;
                float v = acc[mi][nj][r];
                if (HAS_BIAS) v += bias[col];
                C[(size_t)row * Nc + col] = v;
            }
        }
    }
}

// ---------------------------------------------------------------------------
// Fused flash attention, split-bf16 MFMA. Round-7 changes vs validated r6:
//  * Q fragments live in REGISTERS (per-wave ownership) — Q LDS removed.
//  * P is wave-private (wave w touches rows w*32..+31 only) — barrier dropped.
//  * V transpose staged as packed u32 key-pairs (16 b32 stores, was 64 b16).
// LDS = K(18.4K) + V(18.4K) + P32(34.8K) = 70KB -> 2 blocks/CU, 8 waves/CU.
// Fragment layouts identical to the validated GEMM/r6-attn.
// ---------------------------------------------------------------------------
__global__ __launch_bounds__(256, 2) void attn_mfma(const float* __restrict__ qkv,
                                                    float* __restrict__ o) {
    __shared__ __align__(16) __bf16 Khi[64][72];
    __shared__ __align__(16) __bf16 Klo[64][72];
    __shared__ __align__(16) __bf16 Vhi[64][72];   // [dim][key]
    __shared__ __align__(16) __bf16 Vlo[64][72];   // [dim][key]
    __shared__ __align__(16) unsigned int P32[128][68];

    // 512 blocks = 16 qtiles x 16 heads x 2 batch; XCD swizzle (512 % 8 == 0)
    const int nwg  = gridDim.x;
    const int orig = blockIdx.x;
    const int tile = (orig & 7) * (nwg >> 3) + (orig >> 3);
    const int qt = tile & 15;
    const int h  = (tile >> 4) & 15;
    const int b  = tile >> 8;

    const int t  = threadIdx.x;
    const int w  = t >> 6;
    const int l  = t & 63;
    const int lr = l & 15;
    const int kg = l >> 4;
    const int wq = w * 32;              // wave's q-row base within tile

    const size_t bbase = (size_t)b * SEQ * 3 * DIM;
    const int    hoff  = h * HDIM;

    // ---- Q fragments straight into registers (scaled by 1/8, split hi/lo)
    bf16x8 qfh[2][2], qfl[2][2];
#pragma unroll
    for (int mi = 0; mi < 2; ++mi) {
#pragma unroll
        for (int ks = 0; ks < 2; ++ks) {
            const float* qp = qkv + bbase +
                (size_t)(qt * 128 + wq + mi * 16 + lr) * (3 * DIM) + hoff + ks * 32 + kg * 8;
            const float4 v0 = *reinterpret_cast<const float4*>(qp);
            const float4 v1 = *reinterpret_cast<const float4*>(qp + 4);
            const float f[8] = {v0.x, v0.y, v0.z, v0.w, v1.x, v1.y, v1.z, v1.w};
            Bf8 hh, ll;
#pragma unroll
            for (int e = 0; e < 8; ++e)
                split_bf(f[e] * 0.125f, hh.e[e], ll.e[e]);
            qfh[mi][ks] = hh.v;
            qfl[mi][ks] = ll.v;
        }
    }

    // staging assignments: K row-major (thread: key t>>2, 16 dims);
    // V transposed (thread: key-pair t&31, 8 dims at (t>>5)*8)
    const int skey = t >> 2;
    const int sd0  = (t & 3) * 16;
    const int vkp  = (t & 31) * 2;      // key pair base
    const int vd0  = (t >> 5) * 8;      // 8 dims

    const float* kptr  = qkv + bbase + DIM + hoff + (size_t)skey * (3 * DIM) + sd0;
    const float* vptr0 = qkv + bbase + 2 * DIM + hoff + (size_t)(vkp + 0) * (3 * DIM) + vd0;
    const float* vptr1 = qkv + bbase + 2 * DIM + hoff + (size_t)(vkp + 1) * (3 * DIM) + vd0;
    const size_t kvstep = (size_t)64 * 3 * DIM;   // 64 keys per tile

    float4 kreg[4], vreg[4];
#pragma unroll
    for (int i = 0; i < 4; ++i) kreg[i] = *reinterpret_cast<const float4*>(kptr + i * 4);
    vreg[0] = *reinterpret_cast<const float4*>(vptr0);
    vreg[1] = *reinterpret_cast<const float4*>(vptr0 + 4);
    vreg[2] = *reinterpret_cast<const float4*>(vptr1);
    vreg[3] = *reinterpret_cast<const float4*>(vptr1 + 4);

    f32x4 oacc[2][4] = {};
    float mrow[2][4], lrow[2][4];
#pragma unroll
    for (int mi = 0; mi < 2; ++mi)
#pragma unroll
        for (int r = 0; r < 4; ++r) { mrow[mi][r] = -INFINITY; lrow[mi][r] = 0.f; }

    for (int kt = 0; kt < SEQ / 64; ++kt) {
        __syncthreads();   // all waves done reading K/V of previous tile

        // ---- write K tile (split hi/lo, row-major [key][dim])
#pragma unroll
        for (int c = 0; c < 2; ++c) {
            Bf8 hh, ll;
#pragma unroll
            for (int q = 0; q < 2; ++q) {
                const float4 v = kreg[c * 2 + q];
                const float f[4] = {v.x, v.y, v.z, v.w};
#pragma unroll
                for (int e = 0; e < 4; ++e)
                    split_bf(f[e], hh.e[q * 4 + e], ll.e[q * 4 + e]);
            }
            *reinterpret_cast<bf16x8*>(&Khi[skey][sd0 + c * 8]) = hh.v;
            *reinterpret_cast<bf16x8*>(&Klo[skey][sd0 + c * 8]) = ll.v;
        }
        // ---- write V tile transposed: packed u32 = {key vkp, key vkp+1}
        {
            const float f0[8] = {vreg[0].x, vreg[0].y, vreg[0].z, vreg[0].w,
                                 vreg[1].x, vreg[1].y, vreg[1].z, vreg[1].w};
            const float f1[8] = {vreg[2].x, vreg[2].y, vreg[2].z, vreg[2].w,
                                 vreg[3].x, vreg[3].y, vreg[3].z, vreg[3].w};
#pragma unroll
            for (int e = 0; e < 8; ++e) {
                __bf16 h0, l0, h1, l1;
                split_bf(f0[e], h0, l0);
                split_bf(f1[e], h1, l1);
                Bf1 a, c2;
                a.b = h0; c2.b = h1;
                *reinterpret_cast<unsigned int*>(&Vhi[vd0 + e][vkp]) =
                    (unsigned int)a.u | ((unsigned int)c2.u << 16);
                a.b = l0; c2.b = l1;
                *reinterpret_cast<unsigned int*>(&Vlo[vd0 + e][vkp]) =
                    (unsigned int)a.u | ((unsigned int)c2.u << 16);
            }
        }
        __syncthreads();   // K/V ready

        // ---- prefetch next K/V tile into registers (hides HBM under compute)
        if (kt < SEQ / 64 - 1) {
            const float* kp  = kptr  + (size_t)(kt + 1) * kvstep;
            const float* vp0 = vptr0 + (size_t)(kt + 1) * kvstep;
            const float* vp1 = vptr1 + (size_t)(kt + 1) * kvstep;
#pragma unroll
            for (int i = 0; i < 4; ++i) kreg[i] = *reinterpret_cast<const float4*>(kp + i * 4);
            vreg[0] = *reinterpret_cast<const float4*>(vp0);
            vreg[1] = *reinterpret_cast<const float4*>(vp0 + 4);
            vreg[2] = *reinterpret_cast<const float4*>(vp1);
            vreg[3] = *reinterpret_cast<const float4*>(vp1 + 4);
        }

        // ---- S = Q K^T  (3-term split; Q from registers)
        f32x4 sacc[2][4] = {};
#pragma unroll
        for (int ks = 0; ks < 2; ++ks) {
#pragma unroll
            for (int nj = 0; nj < 4; ++nj) {
                const bf16x8 kh = *reinterpret_cast<const bf16x8*>(&Khi[nj * 16 + lr][ks * 32 + kg * 8]);
                const bf16x8 kl = *reinterpret_cast<const bf16x8*>(&Klo[nj * 16 + lr][ks * 32 + kg * 8]);
#pragma unroll
                for (int mi = 0; mi < 2; ++mi) {
                    sacc[mi][nj] = __builtin_amdgcn_mfma_f32_16x16x32_bf16(qfh[mi][ks], kh, sacc[mi][nj], 0, 0, 0);
                    sacc[mi][nj] = __builtin_amdgcn_mfma_f32_16x16x32_bf16(qfl[mi][ks], kh, sacc[mi][nj], 0, 0, 0);
                    sacc[mi][nj] = __builtin_amdgcn_mfma_f32_16x16x32_bf16(qfh[mi][ks], kl, sacc[mi][nj], 0, 0, 0);
                }
            }
        }

        // ---- online softmax (rows at (mi, kg, r); keys = nj*16 + l&15)
#pragma unroll
        for (int mi = 0; mi < 2; ++mi) {
#pragma unroll
            for (int r = 0; r < 4; ++r) {
                const float s0 = sacc[mi][0][r], s1 = sacc[mi][1][r];
                const float s2 = sacc[mi][2][r], s3 = sacc[mi][3][r];
                float pm = fmaxf(fmaxf(s0, s1), fmaxf(s2, s3));
                pm = fmaxf(pm, __shfl_xor(pm, 1));
                pm = fmaxf(pm, __shfl_xor(pm, 2));
                pm = fmaxf(pm, __shfl_xor(pm, 4));
                pm = fmaxf(pm, __shfl_xor(pm, 8));
                const float nm = fmaxf(mrow[mi][r], pm);
                const float p0 = __expf(s0 - nm), p1 = __expf(s1 - nm);
                const float p2 = __expf(s2 - nm), p3 = __expf(s3 - nm);
                float ls = (p0 + p1) + (p2 + p3);
                ls += __shfl_xor(ls, 1);
                ls += __shfl_xor(ls, 2);
                ls += __shfl_xor(ls, 4);
                ls += __shfl_xor(ls, 8);
                const float fac = __expf(mrow[mi][r] - nm);
                mrow[mi][r] = nm;
                lrow[mi][r] = lrow[mi][r] * fac + ls;
#pragma unroll
                for (int njd = 0; njd < 4; ++njd) oacc[mi][njd][r] *= fac;
                const int prow = wq + mi * 16 + kg * 4 + r;
                P32[prow][0 * 16 + lr] = pack_bf(p0);
                P32[prow][1 * 16 + lr] = pack_bf(p1);
                P32[prow][2 * 16 + lr] = pack_bf(p2);
                P32[prow][3 * 16 + lr] = pack_bf(p3);
            }
        }
        // NO barrier: P rows are wave-private (write+read by the same wave);
        // in-wave LDS ordering + compiler lgkmcnt handles the dependency.

        // ---- O += P V  (A = P[row][key], B = V^T[dim][key])
#pragma unroll
        for (int ks = 0; ks < 2; ++ks) {
            bf16x8 ph[2], pl[2];
#pragma unroll
            for (int mi = 0; mi < 2; ++mi) {
                const unsigned int* pp = &P32[wq + mi * 16 + lr][ks * 32 + kg * 8];
                const uint4 u0 = *reinterpret_cast<const uint4*>(pp);
                const uint4 u1 = *reinterpret_cast<const uint4*>(pp + 4);
                const unsigned int uu[8] = {u0.x, u0.y, u0.z, u0.w, u1.x, u1.y, u1.z, u1.w};
                Bf8 hh, ll;
#pragma unroll
                for (int j = 0; j < 8; ++j) {
                    hh.us[j] = (unsigned short)(uu[j] & 0xffffu);
                    ll.us[j] = (unsigned short)(uu[j] >> 16);
                }
                ph[mi] = hh.v;
                pl[mi] = ll.v;
            }
#pragma unroll
            for (int njd = 0; njd < 4; ++njd) {
                const bf16x8 vh = *reinterpret_cast<const bf16x8*>(&Vhi[njd * 16 + lr][ks * 32 + kg * 8]);
                const bf16x8 vl = *reinterpret_cast<const bf16x8*>(&Vlo[njd * 16 + lr][ks * 32 + kg * 8]);
#pragma unroll
                for (int mi = 0; mi < 2; ++mi) {
                    oacc[mi][njd] = __builtin_amdgcn_mfma_f32_16x16x32_bf16(ph[mi], vh, oacc[mi][njd], 0, 0, 0);
                    oacc[mi][njd] = __builtin_amdgcn_mfma_f32_16x16x32_bf16(pl[mi], vh, oacc[mi][njd], 0, 0, 0);
                    oacc[mi][njd] = __builtin_amdgcn_mfma_f32_16x16x32_bf16(ph[mi], vl, oacc[mi][njd], 0, 0, 0);
                }
            }
        }
    }

    // ---- epilogue: normalize and write O [B*SEQ, DIM] head-major cols
#pragma unroll
    for (int mi = 0; mi < 2; ++mi) {
#pragma unroll
        for (int r = 0; r < 4; ++r) {
            const float inv = 1.f / lrow[mi][r];
            const int grow = b * SEQ + qt * 128 + wq + mi * 16 + kg * 4 + r;
#pragma unroll
            for (int njd = 0; njd < 4; ++njd)
                o[(size_t)grow * DIM + hoff + njd * 16 + lr] = oacc[mi][njd][r] * inv;
        }
    }
}

// ---------------------------------------------------------------------------
extern "C" void kernel_launch(void* const* d_in, const int* in_sizes, int n_in,
                              void* d_out, int out_size, void* d_ws, size_t ws_size,
                              hipStream_t stream) {
    const float* x      = (const float*)d_in[0];   // [2,2048,1024]
    const float* w_qkv  = (const float*)d_in[1];   // [3072,1024]
    const float* w_proj = (const float*)d_in[2];   // [1024,1024]
    const float* b_proj = (const float*)d_in[3];   // [1024]
    float* out = (float*)d_out;                    // [2,2048,1024]

    const int M = NB * SEQ;                        // 4096
    float* qkv  = (float*)d_ws;                    // [4096, 3072]
    float* obuf = qkv + (size_t)M * 3 * DIM;       // [4096, 1024]

    // 1) QKV projection: 768 blocks (%8==0)
    gemm_nt_mfma<false><<<dim3((M / 128) * (3 * DIM / 128)), 256, 0, stream>>>(
        x, w_qkv, nullptr, qkv, M, 3 * DIM, DIM);

    // 2) fused attention: 512 blocks (%8==0)
    attn_mfma<<<dim3((SEQ / 128) * NHEADS * NB), 256, 0, stream>>>(qkv, obuf);

    // 3) output projection + bias: 256 blocks (%8==0)
    gemm_nt_mfma<true><<<dim3((M / 128) * (DIM / 128)), 256, 0, stream>>>(
        obuf, w_proj, b_proj, out, M, DIM, DIM);
}

// Round 9
// 365.615 us; speedup vs baseline: 2.8160x; 1.1049x over previous
//
#include <hip/hip_runtime.h>
#include <cmath>

#define DIM 1024
#define NHEADS 16
#define HDIM 64
#define NB 2
#define SEQ 2048
// M = NB*SEQ = 4096 rows through both GEMMs

typedef __bf16 bf16x8 __attribute__((ext_vector_type(8)));
typedef __bf16 bf16x4 __attribute__((ext_vector_type(4)));
typedef float f32x4 __attribute__((ext_vector_type(4)));

union Bf8 { bf16x8 v; __bf16 e[8]; unsigned short us[8]; };
union Bf4 { bf16x4 v; __bf16 e[4]; };

__device__ __forceinline__ void split_bf(float f, __bf16 &h, __bf16 &l) {
    h = (__bf16)f;
    l = (__bf16)(f - (float)h);
}
__device__ __forceinline__ unsigned int pack_bf(float f) {
    __bf16 h, l;
    split_bf(f, h, l);
    union { __bf16 b; unsigned short u; } ch, cl;
    ch.b = h; cl.b = l;
    return (unsigned int)ch.u | ((unsigned int)cl.u << 16);
}

// ---------------------------------------------------------------------------
// Prepass: split an f32 array into hi/lo bf16 planes (full-ws path only).
// ---------------------------------------------------------------------------
__global__ __launch_bounds__(256) void split_f32(const float* __restrict__ in,
                                                 __bf16* __restrict__ hi,
                                                 __bf16* __restrict__ lo, int n4) {
    for (int i = blockIdx.x * blockDim.x + threadIdx.x; i < n4;
         i += gridDim.x * blockDim.x) {
        const float4 v = reinterpret_cast<const float4*>(in)[i];
        const float f[4] = {v.x, v.y, v.z, v.w};
        Bf4 h, l;
#pragma unroll
        for (int e = 0; e < 4; ++e) split_bf(f[e], h.e[e], l.e[e]);
        reinterpret_cast<bf16x4*>(hi)[i] = h.v;
        reinterpret_cast<bf16x4*>(lo)[i] = l.v;
    }
}

// ---------------------------------------------------------------------------
// Split-bf16 MFMA GEMM (NT): C = A * W^T. Same validated structure as r4/r8;
// staging/epilogue paths templated:
//   SA/SB : operand pre-split (bf16 hi/lo planes) -> staging is a pure copy
//   SOUT  : epilogue writes hi/lo bf16 planes (+QSCALE: cols<DIM scaled 1/8)
//   else  : f32 out (+bias)
// ---------------------------------------------------------------------------
template <bool SA, bool SB, bool SOUT, bool QSCALE, bool HAS_BIAS>
__global__ __launch_bounds__(256) void gemm_nt_mfma(
    const float* __restrict__ Af, const __bf16* __restrict__ Agh, const __bf16* __restrict__ Agl,
    const float* __restrict__ Bf, const __bf16* __restrict__ Bgh, const __bf16* __restrict__ Bgl,
    const float* __restrict__ bias,
    float* __restrict__ Cf, __bf16* __restrict__ Cgh, __bf16* __restrict__ Cgl,
    int M, int Nc, int K) {
    __shared__ __align__(16) __bf16 Ah[128][40];
    __shared__ __align__(16) __bf16 Al[128][40];
    __shared__ __align__(16) __bf16 Bh[128][40];
    __shared__ __align__(16) __bf16 Bl[128][40];

    const int nwg  = gridDim.x;
    const int orig = blockIdx.x;
    const int tile = (orig & 7) * (nwg >> 3) + (orig >> 3);
    const int gx   = Nc >> 7;
    const int m0   = (tile / gx) * 128;
    const int n0   = (tile % gx) * 128;

    const int t  = threadIdx.x;
    const int w  = t >> 6;
    const int l  = t & 63;
    const int wr = (w >> 1) * 64;
    const int wc = (w & 1) * 64;
    const int lr = l & 15;
    const int kg = l >> 4;

    const int srow = t >> 1;
    const int skh  = (t & 1) * 16;
    const size_t arow = (size_t)(m0 + srow) * K + skh;
    const size_t brow = (size_t)(n0 + srow) * K + skh;

    f32x4 acc[4][4] = {};

    for (int k0 = 0; k0 < K; k0 += 32) {
        float4 av[4], bv[4];
        bf16x8 sah[2], sal[2], sbh[2], sbl[2];
        if constexpr (SA) {
            sah[0] = *reinterpret_cast<const bf16x8*>(Agh + arow + k0);
            sah[1] = *reinterpret_cast<const bf16x8*>(Agh + arow + k0 + 8);
            sal[0] = *reinterpret_cast<const bf16x8*>(Agl + arow + k0);
            sal[1] = *reinterpret_cast<const bf16x8*>(Agl + arow + k0 + 8);
        } else {
#pragma unroll
            for (int i = 0; i < 4; ++i)
                av[i] = *reinterpret_cast<const float4*>(Af + arow + k0 + i * 4);
        }
        if constexpr (SB) {
            sbh[0] = *reinterpret_cast<const bf16x8*>(Bgh + brow + k0);
            sbh[1] = *reinterpret_cast<const bf16x8*>(Bgh + brow + k0 + 8);
            sbl[0] = *reinterpret_cast<const bf16x8*>(Bgl + brow + k0);
            sbl[1] = *reinterpret_cast<const bf16x8*>(Bgl + brow + k0 + 8);
        } else {
#pragma unroll
            for (int i = 0; i < 4; ++i)
                bv[i] = *reinterpret_cast<const float4*>(Bf + brow + k0 + i * 4);
        }
        __syncthreads();  // previous iteration done reading LDS

        if constexpr (SA) {
            *reinterpret_cast<bf16x8*>(&Ah[srow][skh])     = sah[0];
            *reinterpret_cast<bf16x8*>(&Ah[srow][skh + 8]) = sah[1];
            *reinterpret_cast<bf16x8*>(&Al[srow][skh])     = sal[0];
            *reinterpret_cast<bf16x8*>(&Al[srow][skh + 8]) = sal[1];
        } else {
#pragma unroll
            for (int half = 0; half < 2; ++half) {
                Bf8 hh, ll;
#pragma unroll
                for (int q = 0; q < 2; ++q) {
                    const float4 va = av[half * 2 + q];
                    const float fa[4] = {va.x, va.y, va.z, va.w};
#pragma unroll
                    for (int e = 0; e < 4; ++e)
                        split_bf(fa[e], hh.e[q * 4 + e], ll.e[q * 4 + e]);
                }
                *reinterpret_cast<bf16x8*>(&Ah[srow][skh + half * 8]) = hh.v;
                *reinterpret_cast<bf16x8*>(&Al[srow][skh + half * 8]) = ll.v;
            }
        }
        if constexpr (SB) {
            *reinterpret_cast<bf16x8*>(&Bh[srow][skh])     = sbh[0];
            *reinterpret_cast<bf16x8*>(&Bh[srow][skh + 8]) = sbh[1];
            *reinterpret_cast<bf16x8*>(&Bl[srow][skh])     = sbl[0];
            *reinterpret_cast<bf16x8*>(&Bl[srow][skh + 8]) = sbl[1];
        } else {
#pragma unroll
            for (int half = 0; half < 2; ++half) {
                Bf8 hh, ll;
#pragma unroll
                for (int q = 0; q < 2; ++q) {
                    const float4 vb = bv[half * 2 + q];
                    const float fb[4] = {vb.x, vb.y, vb.z, vb.w};
#pragma unroll
                    for (int e = 0; e < 4; ++e)
                        split_bf(fb[e], hh.e[q * 4 + e], ll.e[q * 4 + e]);
                }
                *reinterpret_cast<bf16x8*>(&Bh[srow][skh + half * 8]) = hh.v;
                *reinterpret_cast<bf16x8*>(&Bl[srow][skh + half * 8]) = ll.v;
            }
        }
        __syncthreads();  // tiles ready

        bf16x8 fah[4], fal[4], fbh[4], fbl[4];
#pragma unroll
        for (int mi = 0; mi < 4; ++mi) {
            fah[mi] = *reinterpret_cast<const bf16x8*>(&Ah[wr + mi * 16 + lr][kg * 8]);
            fal[mi] = *reinterpret_cast<const bf16x8*>(&Al[wr + mi * 16 + lr][kg * 8]);
        }
#pragma unroll
        for (int nj = 0; nj < 4; ++nj) {
            fbh[nj] = *reinterpret_cast<const bf16x8*>(&Bh[wc + nj * 16 + lr][kg * 8]);
            fbl[nj] = *reinterpret_cast<const bf16x8*>(&Bl[wc + nj * 16 + lr][kg * 8]);
        }
#pragma unroll
        for (int mi = 0; mi < 4; ++mi)
#pragma unroll
            for (int nj = 0; nj < 4; ++nj) {
                acc[mi][nj] = __builtin_amdgcn_mfma_f32_16x16x32_bf16(
                    fah[mi], fbh[nj], acc[mi][nj], 0, 0, 0);
                acc[mi][nj] = __builtin_amdgcn_mfma_f32_16x16x32_bf16(
                    fal[mi], fbh[nj], acc[mi][nj], 0, 0, 0);
                acc[mi][nj] = __builtin_amdgcn_mfma_f32_16x16x32_bf16(
                    fah[mi], fbl[nj], acc[mi][nj], 0, 0, 0);
            }
    }

    const int orw = kg * 4;
#pragma unroll
    for (int mi = 0; mi < 4; ++mi) {
#pragma unroll
        for (int r = 0; r < 4; ++r) {
            const int row = m0 + wr + mi * 16 + orw + r;
#pragma unroll
            for (int nj = 0; nj < 4; ++nj) {
                const int col = n0 + wc + nj * 16 + lr;
                float v = acc[mi][nj][r];
                if constexpr (SOUT) {
                    if constexpr (QSCALE) {
                        if (col < DIM) v *= 0.125f;   // fold attention 1/sqrt(64)
                    }
                    __bf16 hh, ll;
                    split_bf(v, hh, ll);
                    const size_t off = (size_t)row * Nc + col;
                    Cgh[off] = hh;
                    Cgl[off] = ll;
                } else {
                    if constexpr (HAS_BIAS) v += bias[col];
                    Cf[(size_t)row * Nc + col] = v;
                }
            }
        }
    }
}

// ---------------------------------------------------------------------------
// Fused flash attention, split-bf16 MFMA. r9: consumes PRE-SPLIT qkv hi/lo
// planes (Q already scaled by GEMM1) -> staging is copies + shift/or packs,
// no float->bf16 conversion in the loop. Writes obuf as hi/lo planes.
// Structure/barriers/fragment layouts identical to validated r8.
// ---------------------------------------------------------------------------
__global__ __launch_bounds__(256, 2) void attn_mfma(const __bf16* __restrict__ qkv_hi,
                                                    const __bf16* __restrict__ qkv_lo,
                                                    __bf16* __restrict__ o_hi,
                                                    __bf16* __restrict__ o_lo) {
    __shared__ __align__(16) __bf16 Khi[64][72];
    __shared__ __align__(16) __bf16 Klo[64][72];
    __shared__ __align__(16) __bf16 Vhi[64][72];   // [dim][key]
    __shared__ __align__(16) __bf16 Vlo[64][72];   // [dim][key]
    __shared__ __align__(16) unsigned int P32[128][68];

    const int nwg  = gridDim.x;
    const int orig = blockIdx.x;
    const int tile = (orig & 7) * (nwg >> 3) + (orig >> 3);
    const int qt = tile & 15;
    const int h  = (tile >> 4) & 15;
    const int b  = tile >> 8;

    const int t  = threadIdx.x;
    const int w  = t >> 6;
    const int l  = t & 63;
    const int lr = l & 15;
    const int kg = l >> 4;
    const int wq = w * 32;

    const size_t bbase = (size_t)b * SEQ * 3 * DIM;
    const int    hoff  = h * HDIM;

    // ---- Q fragments: direct pre-split loads (already scaled by 1/8)
    bf16x8 qfh[2][2], qfl[2][2];
#pragma unroll
    for (int mi = 0; mi < 2; ++mi) {
#pragma unroll
        for (int ks = 0; ks < 2; ++ks) {
            const size_t qoff = bbase +
                (size_t)(qt * 128 + wq + mi * 16 + lr) * (3 * DIM) + hoff + ks * 32 + kg * 8;
            qfh[mi][ks] = *reinterpret_cast<const bf16x8*>(qkv_hi + qoff);
            qfl[mi][ks] = *reinterpret_cast<const bf16x8*>(qkv_lo + qoff);
        }
    }

    // staging: K row-major (thread: key t>>2, 16 dims); V transposed
    // (thread: key-pair t&31 offset *2, 8 dims at (t>>5)*8)
    const int skey = t >> 2;
    const int sd0  = (t & 3) * 16;
    const int vkp  = (t & 31) * 2;
    const int vd0  = (t >> 5) * 8;

    const size_t koff  = bbase + DIM + hoff + (size_t)skey * (3 * DIM) + sd0;
    const size_t voff0 = bbase + 2 * DIM + hoff + (size_t)(vkp + 0) * (3 * DIM) + vd0;
    const size_t voff1 = bbase + 2 * DIM + hoff + (size_t)(vkp + 1) * (3 * DIM) + vd0;
    const size_t kvstep = (size_t)64 * 3 * DIM;

    bf16x8 kr[4], vr[4];
    kr[0] = *reinterpret_cast<const bf16x8*>(qkv_hi + koff);
    kr[1] = *reinterpret_cast<const bf16x8*>(qkv_hi + koff + 8);
    kr[2] = *reinterpret_cast<const bf16x8*>(qkv_lo + koff);
    kr[3] = *reinterpret_cast<const bf16x8*>(qkv_lo + koff + 8);
    vr[0] = *reinterpret_cast<const bf16x8*>(qkv_hi + voff0);
    vr[1] = *reinterpret_cast<const bf16x8*>(qkv_hi + voff1);
    vr[2] = *reinterpret_cast<const bf16x8*>(qkv_lo + voff0);
    vr[3] = *reinterpret_cast<const bf16x8*>(qkv_lo + voff1);

    f32x4 oacc[2][4] = {};
    float mrow[2][4], lrow[2][4];
#pragma unroll
    for (int mi = 0; mi < 2; ++mi)
#pragma unroll
        for (int r = 0; r < 4; ++r) { mrow[mi][r] = -INFINITY; lrow[mi][r] = 0.f; }

    for (int kt = 0; kt < SEQ / 64; ++kt) {
        __syncthreads();   // all waves done reading K/V of previous tile

        // ---- K tile: pure b128 copies
        *reinterpret_cast<bf16x8*>(&Khi[skey][sd0])     = kr[0];
        *reinterpret_cast<bf16x8*>(&Khi[skey][sd0 + 8]) = kr[1];
        *reinterpret_cast<bf16x8*>(&Klo[skey][sd0])     = kr[2];
        *reinterpret_cast<bf16x8*>(&Klo[skey][sd0 + 8]) = kr[3];
        // ---- V tile transposed: pack 2 keys per u32, shift/or only
        {
            Bf8 k0h, k1h, k0l, k1l;
            k0h.v = vr[0]; k1h.v = vr[1]; k0l.v = vr[2]; k1l.v = vr[3];
#pragma unroll
            for (int e = 0; e < 8; ++e) {
                *reinterpret_cast<unsigned int*>(&Vhi[vd0 + e][vkp]) =
                    (unsigned int)k0h.us[e] | ((unsigned int)k1h.us[e] << 16);
                *reinterpret_cast<unsigned int*>(&Vlo[vd0 + e][vkp]) =
                    (unsigned int)k0l.us[e] | ((unsigned int)k1l.us[e] << 16);
            }
        }
        __syncthreads();   // K/V ready

        // ---- prefetch next K/V tile
        if (kt < SEQ / 64 - 1) {
            const size_t kk = koff + (size_t)(kt + 1) * kvstep;
            const size_t v0 = voff0 + (size_t)(kt + 1) * kvstep;
            const size_t v1 = voff1 + (size_t)(kt + 1) * kvstep;
            kr[0] = *reinterpret_cast<const bf16x8*>(qkv_hi + kk);
            kr[1] = *reinterpret_cast<const bf16x8*>(qkv_hi + kk + 8);
            kr[2] = *reinterpret_cast<const bf16x8*>(qkv_lo + kk);
            kr[3] = *reinterpret_cast<const bf16x8*>(qkv_lo + kk + 8);
            vr[0] = *reinterpret_cast<const bf16x8*>(qkv_hi + v0);
            vr[1] = *reinterpret_cast<const bf16x8*>(qkv_hi + v1);
            vr[2] = *reinterpret_cast<const bf16x8*>(qkv_lo + v0);
            vr[3] = *reinterpret_cast<const bf16x8*>(qkv_lo + v1);
        }

        // ---- S = Q K^T  (3-term split)
        f32x4 sacc[2][4] = {};
#pragma unroll
        for (int ks = 0; ks < 2; ++ks) {
#pragma unroll
            for (int nj = 0; nj < 4; ++nj) {
                const bf16x8 kh = *reinterpret_cast<const bf16x8*>(&Khi[nj * 16 + lr][ks * 32 + kg * 8]);
                const bf16x8 kl = *reinterpret_cast<const bf16x8*>(&Klo[nj * 16 + lr][ks * 32 + kg * 8]);
#pragma unroll
                for (int mi = 0; mi < 2; ++mi) {
                    sacc[mi][nj] = __builtin_amdgcn_mfma_f32_16x16x32_bf16(qfh[mi][ks], kh, sacc[mi][nj], 0, 0, 0);
                    sacc[mi][nj] = __builtin_amdgcn_mfma_f32_16x16x32_bf16(qfl[mi][ks], kh, sacc[mi][nj], 0, 0, 0);
                    sacc[mi][nj] = __builtin_amdgcn_mfma_f32_16x16x32_bf16(qfh[mi][ks], kl, sacc[mi][nj], 0, 0, 0);
                }
            }
        }

        // ---- online softmax
#pragma unroll
        for (int mi = 0; mi < 2; ++mi) {
#pragma unroll
            for (int r = 0; r < 4; ++r) {
                const float s0 = sacc[mi][0][r], s1 = sacc[mi][1][r];
                const float s2 = sacc[mi][2][r], s3 = sacc[mi][3][r];
                float pm = fmaxf(fmaxf(s0, s1), fmaxf(s2, s3));
                pm = fmaxf(pm, __shfl_xor(pm, 1));
                pm = fmaxf(pm, __shfl_xor(pm, 2));
                pm = fmaxf(pm, __shfl_xor(pm, 4));
                pm = fmaxf(pm, __shfl_xor(pm, 8));
                const float nm = fmaxf(mrow[mi][r], pm);
                const float p0 = __expf(s0 - nm), p1 = __expf(s1 - nm);
                const float p2 = __expf(s2 - nm), p3 = __expf(s3 - nm);
                float ls = (p0 + p1) + (p2 + p3);
                ls += __shfl_xor(ls, 1);
                ls += __shfl_xor(ls, 2);
                ls += __shfl_xor(ls, 4);
                ls += __shfl_xor(ls, 8);
                const float fac = __expf(mrow[mi][r] - nm);
                mrow[mi][r] = nm;
                lrow[mi][r] = lrow[mi][r] * fac + ls;
#pragma unroll
                for (int njd = 0; njd < 4; ++njd) oacc[mi][njd][r] *= fac;
                const int prow = wq + mi * 16 + kg * 4 + r;
                P32[prow][0 * 16 + lr] = pack_bf(p0);
                P32[prow][1 * 16 + lr] = pack_bf(p1);
                P32[prow][2 * 16 + lr] = pack_bf(p2);
                P32[prow][3 * 16 + lr] = pack_bf(p3);
            }
        }
        // NO barrier: P rows are wave-private.

        // ---- O += P V
#pragma unroll
        for (int ks = 0; ks < 2; ++ks) {
            bf16x8 ph[2], pl[2];
#pragma unroll
            for (int mi = 0; mi < 2; ++mi) {
                const unsigned int* pp = &P32[wq + mi * 16 + lr][ks * 32 + kg * 8];
                const uint4 u0 = *reinterpret_cast<const uint4*>(pp);
                const uint4 u1 = *reinterpret_cast<const uint4*>(pp + 4);
                const unsigned int uu[8] = {u0.x, u0.y, u0.z, u0.w, u1.x, u1.y, u1.z, u1.w};
                Bf8 hh, ll;
#pragma unroll
                for (int j = 0; j < 8; ++j) {
                    hh.us[j] = (unsigned short)(uu[j] & 0xffffu);
                    ll.us[j] = (unsigned short)(uu[j] >> 16);
                }
                ph[mi] = hh.v;
                pl[mi] = ll.v;
            }
#pragma unroll
            for (int njd = 0; njd < 4; ++njd) {
                const bf16x8 vh = *reinterpret_cast<const bf16x8*>(&Vhi[njd * 16 + lr][ks * 32 + kg * 8]);
                const bf16x8 vl = *reinterpret_cast<const bf16x8*>(&Vlo[njd * 16 + lr][ks * 32 + kg * 8]);
#pragma unroll
                for (int mi = 0; mi < 2; ++mi) {
                    oacc[mi][njd] = __builtin_amdgcn_mfma_f32_16x16x32_bf16(ph[mi], vh, oacc[mi][njd], 0, 0, 0);
                    oacc[mi][njd] = __builtin_amdgcn_mfma_f32_16x16x32_bf16(pl[mi], vh, oacc[mi][njd], 0, 0, 0);
                    oacc[mi][njd] = __builtin_amdgcn_mfma_f32_16x16x32_bf16(ph[mi], vl, oacc[mi][njd], 0, 0, 0);
                }
            }
        }
    }

    // ---- epilogue: normalize, split, write hi/lo planes for proj GEMM
#pragma unroll
    for (int mi = 0; mi < 2; ++mi) {
#pragma unroll
        for (int r = 0; r < 4; ++r) {
            const float inv = 1.f / lrow[mi][r];
            const int grow = b * SEQ + qt * 128 + wq + mi * 16 + kg * 4 + r;
#pragma unroll
            for (int njd = 0; njd < 4; ++njd) {
                const float v = oacc[mi][njd][r] * inv;
                __bf16 hh, ll;
                split_bf(v, hh, ll);
                const size_t off = (size_t)grow * DIM + hoff + njd * 16 + lr;
                o_hi[off] = hh;
                o_lo[off] = ll;
            }
        }
    }
}

// ---------------------------------------------------------------------------
extern "C" void kernel_launch(void* const* d_in, const int* in_sizes, int n_in,
                              void* d_out, int out_size, void* d_ws, size_t ws_size,
                              hipStream_t stream) {
    const float* x      = (const float*)d_in[0];   // [2,2048,1024]
    const float* w_qkv  = (const float*)d_in[1];   // [3072,1024]
    const float* w_proj = (const float*)d_in[2];   // [1024,1024]
    const float* b_proj = (const float*)d_in[3];   // [1024]
    float* out = (float*)d_out;                    // [2,2048,1024]

    const int M = NB * SEQ;                        // 4096
    const size_t qkvN  = (size_t)M * 3 * DIM;      // 12.58M
    const size_t obufN = (size_t)M * DIM;          // 4.19M
    const size_t xN    = (size_t)M * DIM;
    const size_t wqN   = (size_t)(3 * DIM) * DIM;
    const size_t wpN   = (size_t)DIM * DIM;

    __bf16* p = (__bf16*)d_ws;
    __bf16* qkv_hi = p;  p += qkvN;
    __bf16* qkv_lo = p;  p += qkvN;
    __bf16* ob_hi  = p;  p += obufN;
    __bf16* ob_lo  = p;  p += obufN;    // <= here: 67.1 MB (known-good)
    __bf16* x_hi   = p;  p += xN;
    __bf16* x_lo   = p;  p += xN;
    __bf16* wq_hi  = p;  p += wqN;
    __bf16* wq_lo  = p;  p += wqN;
    __bf16* wp_hi  = p;  p += wpN;
    __bf16* wp_lo  = p;  p += wpN;      // full: 100.7 MB
    const size_t NEED_FULL = 2 * (qkvN + obufN + xN + wqN + wpN) * sizeof(__bf16);
    const bool full = ws_size >= NEED_FULL;   // constant per run -> graph-safe

    if (full) {
        // prepass: pre-split inputs/weights (~12 us total)
        split_f32<<<512, 256, 0, stream>>>(x,      x_hi,  x_lo,  (int)(xN / 4));
        split_f32<<<512, 256, 0, stream>>>(w_qkv,  wq_hi, wq_lo, (int)(wqN / 4));
        split_f32<<<256, 256, 0, stream>>>(w_proj, wp_hi, wp_lo, (int)(wpN / 4));
        // 1) QKV projection (conversion-free staging), split+q-scaled output
        gemm_nt_mfma<true, true, true, true, false>
            <<<dim3((M / 128) * (3 * DIM / 128)), 256, 0, stream>>>(
            nullptr, x_hi, x_lo, nullptr, wq_hi, wq_lo,
            nullptr, nullptr, qkv_hi, qkv_lo, M, 3 * DIM, DIM);
    } else {
        // fallback: on-the-fly split staging (r4-validated path)
        gemm_nt_mfma<false, false, true, true, false>
            <<<dim3((M / 128) * (3 * DIM / 128)), 256, 0, stream>>>(
            x, nullptr, nullptr, w_qkv, nullptr, nullptr,
            nullptr, nullptr, qkv_hi, qkv_lo, M, 3 * DIM, DIM);
    }

    // 2) fused attention: 512 blocks
    attn_mfma<<<dim3((SEQ / 128) * NHEADS * NB), 256, 0, stream>>>(
        qkv_hi, qkv_lo, ob_hi, ob_lo);

    // 3) output projection + bias (A pre-split by attn epilogue)
    if (full) {
        gemm_nt_mfma<true, true, false, false, true>
            <<<dim3((M / 128) * (DIM / 128)), 256, 0, stream>>>(
            nullptr, ob_hi, ob_lo, nullptr, wp_hi, wp_lo,
            b_proj, out, nullptr, nullptr, M, DIM, DIM);
    } else {
        gemm_nt_mfma<true, false, false, false, true>
            <<<dim3((M / 128) * (DIM / 128)), 256, 0, stream>>>(
            nullptr, ob_hi, ob_lo, w_proj, nullptr, nullptr,
            b_proj, out, nullptr, nullptr, M, DIM, DIM);
    }
}